// Round 6
// baseline (321.741 us; speedup 1.0000x reference)
//
#include <hip/hip_runtime.h>
#include <stdint.h>

#define BT      128
#define NPATCH  256
#define DV      1024
#define NB      4
#define DB      256
#define NH16    16
#define SCALE   0.125f
#define LNEPS   1e-5f

// ---- ws layout (float element offsets) ----
#define OFF_BWS    16384u      // 16384 bf16 (MFMA B-frags)
#define OFF_PSC    24608u      // 16 nh * 16 ich * 2 partial S/C
#define OFF_DRAW   25120u      // 32768*16
#define OFF_STATS  549408u     // 32768*2 (mu,rstd)
#define OFF_CV     1139232u    // 128*16
#define OFF_DIV    1141280u    // 768
#define OFF_XBAR   1142048u    // 4 slices * 2097152 bf16
#define XSLICE     2097152u    // elements per slice (ushort units)

#define LROW 264               // bf16 per LDS row (256 + 8 pad)

typedef short bf16x8 __attribute__((ext_vector_type(8)));
typedef float f32x4  __attribute__((ext_vector_type(4)));

__device__ __forceinline__ short f2bf(float f) {   // RNE
    union { float f; unsigned u; } v; v.f = f;
    unsigned u = v.u;
    unsigned r = (u + 0x7fffu + ((u >> 16) & 1u)) >> 16;
    return (short)r;
}

// pack two floats -> two truncated bf16 in one v_perm_b32 (MFMA input only)
__device__ __forceinline__ unsigned pk2(float lo, float hi) {
    union { float f; unsigned u; } a, b; a.f = lo; b.f = hi;
    return __builtin_amdgcn_perm(b.u, a.u, 0x07060302u);
}

// ---- P: wq dots + direct bf16 B-frag pack; 256 blocks = 16 nh x 16 ich ----
__global__ __launch_bounds__(256) void kP(const float* __restrict__ Wk,
                                          const float* __restrict__ q,
                                          const float* __restrict__ g,
                                          const float* __restrict__ b,
                                          float* __restrict__ ws) {
    const int nh = blockIdx.x >> 4, ich = blockIdx.x & 15;
    const int n = nh >> 2, h = nh & 3;
    __shared__ float qs[64];
    __shared__ float redS[4], redC[4];
    const int t = threadIdx.x;
    if (t < 64) qs[t] = q[nh * 64 + t];
    __syncthreads();
    const int r = t >> 2, qd = t & 3;
    const int i = ich * 64 + r;
    const float* wrow = Wk + ((size_t)n * DV + i) * DB + h * 64 + qd * 16;
    float acc = 0.f;
    #pragma unroll
    for (int d = 0; d < 16; d += 4) {
        float4 w4 = *(const float4*)(wrow + d);
        acc += w4.x * qs[qd * 16 + d]     + w4.y * qs[qd * 16 + d + 1]
             + w4.z * qs[qd * 16 + d + 2] + w4.w * qs[qd * 16 + d + 3];
    }
    acc += __shfl_xor(acc, 1);
    acc += __shfl_xor(acc, 2);             // full 64-d dot in all 4 qd lanes
    float gw = g[i] * acc;
    if (qd == 0) {
        unsigned short* bws = (unsigned short*)(ws + OFF_BWS);
        const int kt = i >> 5, oct = (r >> 3) & 3, j = r & 7;
        bws[((kt * 64 + oct * 16 + nh) << 3) + j] = (unsigned short)f2bf(gw);
    }
    float mS = (qd == 0) ? gw : 0.f;
    float mC = (qd == 0) ? b[i] * acc : 0.f;
    #pragma unroll
    for (int dd = 4; dd < 64; dd <<= 1) { mS += __shfl_xor(mS, dd); mC += __shfl_xor(mC, dd); }
    const int wave = t >> 6, lane = t & 63;
    if (lane == 0) { redS[wave] = mS; redC[wave] = mC; }
    __syncthreads();
    if (t == 0) {
        ws[OFF_PSC + (nh * 16 + ich) * 2 + 0] = redS[0] + redS[1] + redS[2] + redS[3];
        ws[OFF_PSC + (nh * 16 + ich) * 2 + 1] = redC[0] + redC[1] + redC[2] + redC[3];
    }
}

// ---- A: single-buffer LDS + register prefetch; 512 blocks x 64 rows ----
__global__ __launch_bounds__(256) void kA(const float* __restrict__ x,
                                          float* __restrict__ ws) {
    __shared__ unsigned short xs[64 * LROW];
    const int t = threadIdx.x;
    const int wv = t >> 6, lane = t & 63;
    const int m = lane & 15, oct = lane >> 4;
    const int row0 = blockIdx.x * 64;
    const bf16x8* bfp = (const bf16x8*)((const unsigned short*)(ws + OFF_BWS));
    const float* xb = x + (size_t)row0 * DV;

    float sum[16], sq[16];
    #pragma unroll
    for (int i = 0; i < 16; ++i) { sum[i] = 0.f; sq[i] = 0.f; }
    f32x4 acc = {0.f, 0.f, 0.f, 0.f};
    float4 r[16];

    auto loadr = [&](int c) {
        #pragma unroll
        for (int i = 0; i < 16; ++i)
            r[i] = *(const float4*)(xb + (size_t)(i * 4 + wv) * DV + c * 256 + lane * 4);
    };
    auto commit = [&]() {
        #pragma unroll
        for (int i = 0; i < 16; ++i) {
            float4 v = r[i];
            sum[i] += v.x + v.y + v.z + v.w;
            sq[i]  += v.x * v.x + v.y * v.y + v.z * v.z + v.w * v.w;
            uint2 pk; pk.x = pk2(v.x, v.y); pk.y = pk2(v.z, v.w);
            *(uint2*)&xs[(i * 4 + wv) * LROW + lane * 4] = pk;
        }
    };
    auto comp = [&](int c) {
        #pragma unroll
        for (int kt = 0; kt < 8; ++kt) {
            bf16x8 af = *(const bf16x8*)&xs[(wv * 16 + m) * LROW + kt * 32 + oct * 8];
            bf16x8 bf = bfp[(c * 8 + kt) * 64 + lane];
            acc = __builtin_amdgcn_mfma_f32_16x16x32_bf16(af, bf, acc, 0, 0, 0);
        }
    };

    loadr(0);
    for (int c = 0; c < 4; ++c) {
        __syncthreads();          // prior chunk's LDS reads done
        commit();                 // regs -> LDS (+ LN sums)
        __syncthreads();
        if (c < 3) loadr(c + 1);  // next chunk's global loads in flight
        comp(c);                  // MFMA from LDS
    }

    #pragma unroll
    for (int r2 = 0; r2 < 4; ++r2)
        ws[OFF_DRAW + (size_t)(row0 + wv * 16 + oct * 4 + r2) * 16 + m] = acc[r2];

    #pragma unroll
    for (int i = 0; i < 16; ++i) {
        float s = sum[i], q2 = sq[i];
        #pragma unroll
        for (int d = 1; d < 64; d <<= 1) { s += __shfl_xor(s, d); q2 += __shfl_xor(q2, d); }
        if (lane == 0) {
            const int row = row0 + i * 4 + wv;
            const float mu  = s * (1.f / 1024.f);
            const float var = q2 * (1.f / 1024.f) - mu * mu;
            float2 st; st.x = mu; st.y = rsqrtf(var + LNEPS);
            *(float2*)(ws + OFF_STATS + (size_t)row * 2) = st;
        }
    }
}

// ---- C: softmax rebuilt per block, then zraw pooling; bf16 XBAR store ----
__global__ __launch_bounds__(256) void kC(const float* __restrict__ x,
                                          const float* __restrict__ q,
                                          const float* __restrict__ bk,
                                          float* __restrict__ ws) {
    const int bt = blockIdx.x;
    const int qq = blockIdx.y;             // p-quarter
    const int t = threadIdx.x;
    __shared__ __attribute__((aligned(16))) float s_s[NH16 * NPATCH];   // 16 KB
    __shared__ __attribute__((aligned(16))) float aavg[NB * NPATCH];    // 4 KB
    __shared__ __attribute__((aligned(16))) float w_s[64 * 16];         // 4 KB
    __shared__ __attribute__((aligned(16))) float rstd_s[NPATCH];
    __shared__ __attribute__((aligned(16))) float mrs[NPATCH];
    __shared__ float Ss[NH16], Cbs[NH16];

    {
        const int nh = t >> 4, ich = t & 15;
        float S = ws[OFF_PSC + t * 2 + 0];
        float C = ws[OFF_PSC + t * 2 + 1];
        const int n2 = nh >> 2, h2 = nh & 3;
        const float* bkp = bk + n2 * DB + h2 * 64 + ich * 4;
        const float* qp  = q + nh * 64 + ich * 4;
        C += bkp[0] * qp[0] + bkp[1] * qp[1] + bkp[2] * qp[2] + bkp[3] * qp[3];
        #pragma unroll
        for (int d = 1; d < 16; d <<= 1) { S += __shfl_xor(S, d); C += __shfl_xor(C, d); }
        if (ich == 0) { Ss[nh] = S; Cbs[nh] = C; }
    }
    const size_t row = (size_t)bt * NPATCH + t;
    const float2 st = *(const float2*)(ws + OFF_STATS + row * 2);
    rstd_s[t] = st.y;
    mrs[t] = st.x * st.y;
    __syncthreads();

    const float* dr = ws + OFF_DRAW + row * 16;
    #pragma unroll
    for (int nh = 0; nh < NH16; ++nh)
        s_s[nh * NPATCH + t] = (st.y * (dr[nh] - st.x * Ss[nh]) + Cbs[nh]) * SCALE;
    __syncthreads();

    const int wave = t >> 6, lane = t & 63;
    for (int r = 0; r < 4; ++r) {
        const int nh = wave * 4 + r;
        float4 v = *(float4*)&s_s[nh * NPATCH + lane * 4];
        float mx = fmaxf(fmaxf(v.x, v.y), fmaxf(v.z, v.w));
        for (int d = 1; d < 64; d <<= 1) mx = fmaxf(mx, __shfl_xor(mx, d));
        float e0 = __expf(v.x - mx), e1 = __expf(v.y - mx);
        float e2 = __expf(v.z - mx), e3 = __expf(v.w - mx);
        float s = e0 + e1 + e2 + e3;
        for (int d = 1; d < 64; d <<= 1) s += __shfl_xor(s, d);
        float inv = 1.f / s;
        float4 a; a.x = e0 * inv; a.y = e1 * inv; a.z = e2 * inv; a.w = e3 * inv;
        *(float4*)&s_s[nh * NPATCH + lane * 4] = a;
    }
    __syncthreads();

    if (qq == 0) {
        for (int r = 0; r < 4; ++r) {
            const int nh = wave * 4 + r;
            float4 a4 = *(float4*)&s_s[nh * NPATCH + lane * 4];
            float4 m4 = *(float4*)&mrs[lane * 4];
            float dd = a4.x * m4.x + a4.y * m4.y + a4.z * m4.z + a4.w * m4.w;
            for (int d = 1; d < 64; d <<= 1) dd += __shfl_xor(dd, d);
            if (lane == 0) ws[OFF_CV + bt * NH16 + nh] = dd;
        }
        #pragma unroll
        for (int nb2 = 0; nb2 < NB; ++nb2)
            aavg[nb2 * NPATCH + t] = 0.25f * (s_s[(nb2 * 4 + 0) * NPATCH + t] + s_s[(nb2 * 4 + 1) * NPATCH + t]
                                            + s_s[(nb2 * 4 + 2) * NPATCH + t] + s_s[(nb2 * 4 + 3) * NPATCH + t]);
        __syncthreads();
        if (wave == 0) {
            float nrm[NB];
            #pragma unroll
            for (int nb2 = 0; nb2 < NB; ++nb2) {
                float4 v = *(float4*)&aavg[nb2 * NPATCH + lane * 4];
                float ss = v.x * v.x + v.y * v.y + v.z * v.z + v.w * v.w;
                for (int d = 1; d < 64; d <<= 1) ss += __shfl_xor(ss, d);
                nrm[nb2] = fmaxf(sqrtf(ss), 1e-8f);
            }
            int pi = 0;
            for (int i2 = 0; i2 < NB; ++i2)
                for (int j2 = i2 + 1; j2 < NB; ++j2) {
                    float4 va = *(float4*)&aavg[i2 * NPATCH + lane * 4];
                    float4 vb = *(float4*)&aavg[j2 * NPATCH + lane * 4];
                    float dd = va.x * vb.x + va.y * vb.y + va.z * vb.z + va.w * vb.w;
                    for (int d = 1; d < 64; d <<= 1) dd += __shfl_xor(dd, d);
                    if (lane == 0) ws[OFF_DIV + bt * 6 + pi] = dd / (nrm[i2] * nrm[j2]);
                    ++pi;
                }
        }
    }

    for (int idx = t; idx < 1024; idx += 256) {
        const int p = idx >> 4, nh = idx & 15;
        w_s[idx] = s_s[nh * NPATCH + qq * 64 + p] * rstd_s[qq * 64 + p];
    }
    __syncthreads();

    float4 acc[16];
    #pragma unroll
    for (int i = 0; i < 16; ++i) { acc[i].x = 0.f; acc[i].y = 0.f; acc[i].z = 0.f; acc[i].w = 0.f; }
    const float* xp = x + (size_t)(bt * NPATCH + qq * 64) * DV + t * 4;
    #define FMA4(k, wgt, xv) acc[k].x += (wgt) * xv.x; acc[k].y += (wgt) * xv.y; \
                             acc[k].z += (wgt) * xv.z; acc[k].w += (wgt) * xv.w;
    #define PBLOCK(p, xv) { \
        float4 a0 = *(const float4*)&w_s[(p) * 16 + 0]; \
        float4 a1 = *(const float4*)&w_s[(p) * 16 + 4]; \
        float4 a2 = *(const float4*)&w_s[(p) * 16 + 8]; \
        float4 a3 = *(const float4*)&w_s[(p) * 16 + 12]; \
        FMA4(0, a0.x, xv)  FMA4(1, a0.y, xv)  FMA4(2, a0.z, xv)  FMA4(3, a0.w, xv) \
        FMA4(4, a1.x, xv)  FMA4(5, a1.y, xv)  FMA4(6, a1.z, xv)  FMA4(7, a1.w, xv) \
        FMA4(8, a2.x, xv)  FMA4(9, a2.y, xv)  FMA4(10, a2.z, xv) FMA4(11, a2.w, xv) \
        FMA4(12, a3.x, xv) FMA4(13, a3.y, xv) FMA4(14, a3.z, xv) FMA4(15, a3.w, xv) }
    for (int p = 0; p < 16; ++p) {
        float4 xv0 = *(const float4*)(xp + (size_t)(p +  0) * DV);
        float4 xv1 = *(const float4*)(xp + (size_t)(p + 16) * DV);
        float4 xv2 = *(const float4*)(xp + (size_t)(p + 32) * DV);
        float4 xv3 = *(const float4*)(xp + (size_t)(p + 48) * DV);
        PBLOCK(p, xv0)
        PBLOCK(p + 16, xv1)
        PBLOCK(p + 32, xv2)
        PBLOCK(p + 48, xv3)
    }
    #undef PBLOCK
    #undef FMA4
    // bf16 RNE store (intermediates are L2/L3-resident; halves L2-side traffic)
    unsigned short* xb16 = (unsigned short*)(ws + OFF_XBAR);
    #pragma unroll
    for (int nh = 0; nh < 16; ++nh) {
        float4 a = acc[nh];
        uint2 pk;
        pk.x = (unsigned)(unsigned short)f2bf(a.x) | ((unsigned)(unsigned short)f2bf(a.y) << 16);
        pk.y = (unsigned)(unsigned short)f2bf(a.z) | ((unsigned)(unsigned short)f2bf(a.w) << 16);
        *(uint2*)&xb16[(size_t)qq * XSLICE + ((size_t)bt * NH16 + nh) * DV + t * 4] = pk;
    }
}

// ---- D (merged D1+D2): grid 256 = n(4) x btg(64, 2 bt); 512 threads ----
// Each block computes the FULL 256-dim pooled row for its 2 bt, then @Wo -> out.
// i-reduction split across 2 thread-halves; per-thread gv/bvv (no column split).
__global__ __launch_bounds__(512) void kD(const float* __restrict__ Wv,
                                          const float* __restrict__ Wo,
                                          const float* __restrict__ g,
                                          const float* __restrict__ b,
                                          const float* __restrict__ bv,
                                          const float* __restrict__ bo,
                                          const float* __restrict__ ws,
                                          float* __restrict__ out) {
    const int n = blockIdx.x >> 6, btg = blockIdx.x & 63;
    const int bt0 = btg * 2;
    __shared__ __attribute__((aligned(16))) float zs[2][4][1024];   // 32 KB
    __shared__ __attribute__((aligned(16))) float gs[1024], bs[1024]; // 8 KB
    __shared__ __attribute__((aligned(16))) float red[2][256][4];   // 8 KB
    __shared__ __attribute__((aligned(16))) float pooled[2][256];   // 2 KB
    __shared__ float dred[8];
    const int t = threadIdx.x;
    const unsigned short* xb16 = (const unsigned short*)(ws + OFF_XBAR);

    // zsum load: 2 bt x 4 h x 1024 dims, summed over 4 qq slices (bf16 decode)
    for (int e = t; e < 2048; e += 512) {
        const int bt = e >> 10, rem = e & 1023;
        const int h = rem >> 8, i4 = rem & 255;
        const int nh = n * 4 + h;
        const size_t b0 = ((size_t)(bt0 + bt) * NH16 + nh) * DV + i4 * 4;
        float sx = 0.f, sy = 0.f, sz = 0.f, sw = 0.f;
        #pragma unroll
        for (int qq = 0; qq < 4; ++qq) {
            uint2 pv = *(const uint2*)&xb16[b0 + (size_t)qq * XSLICE];
            union { unsigned u; float f; } c0, c1, c2, c3;
            c0.u = pv.x << 16; c1.u = pv.x & 0xffff0000u;
            c2.u = pv.y << 16; c3.u = pv.y & 0xffff0000u;
            sx += c0.f; sy += c1.f; sz += c2.f; sw += c3.f;
        }
        float4 s; s.x = sx; s.y = sy; s.z = sz; s.w = sw;
        *(float4*)&zs[bt][h][i4 * 4] = s;
    }
    for (int e = t; e < 1024; e += 512) { gs[e] = g[e]; bs[e] = b[e]; }
    __syncthreads();

    const int c = t & 255, half = t >> 8, h = c >> 6, nh = n * 4 + h;
    {
        float a0 = 0.f, a1 = 0.f, gv = 0.f, bvv = 0.f;
        const float* wvp = Wv + ((size_t)n * DV + half * 512) * DB + c;
        const float* z0 = &zs[0][h][half * 512];
        const float* z1 = &zs[1][h][half * 512];
        const float* gp = &gs[half * 512];
        const float* bp = &bs[half * 512];
        #pragma unroll 4
        for (int i = 0; i < 512; ++i) {
            float w  = wvp[(size_t)i * DB];
            float gw = gp[i] * w;
            gv  += gw;
            bvv += bp[i] * w;
            a0  += z0[i] * gw;
            a1  += z1[i] * gw;
        }
        red[half][c][0] = a0; red[half][c][1] = a1;
        red[half][c][2] = gv; red[half][c][3] = bvv;
    }
    // diversity partial sum (block 0, second half-threads)
    float dacc = 0.f;
    if (blockIdx.x == 0 && half == 1)
        for (int idx = c; idx < 768; idx += 256) dacc += ws[OFF_DIV + idx];
    #pragma unroll
    for (int d = 1; d < 64; d <<= 1) dacc += __shfl_xor(dacc, d);
    if ((t & 63) == 0) dred[t >> 6] = dacc;
    __syncthreads();

    if (half == 0) {
        float A0 = red[0][c][0] + red[1][c][0];
        float A1 = red[0][c][1] + red[1][c][1];
        float GV = red[0][c][2] + red[1][c][2];
        float BV = red[0][c][3] + red[1][c][3];
        float base = bv[n * DB + c] + BV;
        float C0 = ws[OFF_CV + (bt0 + 0) * NH16 + nh];
        float C1 = ws[OFF_CV + (bt0 + 1) * NH16 + nh];
        pooled[0][c] = A0 - C0 * GV + base;
        pooled[1][c] = A1 - C1 * GV + base;
    }
    if (blockIdx.x == 0 && t == 0)
        out[131072] = 0.1f * (dred[4] + dred[5] + dred[6] + dred[7]) / 768.f;
    __syncthreads();

    // pooled @ Wo : thread owns out column j = c; c-reduction split by half
    {
        float o0 = 0.f, o1 = 0.f;
        const float* wop = Wo + ((size_t)n * DB + half * 128) * DB + c;
        const float* p0 = &pooled[0][half * 128];
        const float* p1 = &pooled[1][half * 128];
        #pragma unroll 4
        for (int cc = 0; cc < 128; ++cc) {
            float w = wop[(size_t)cc * DB];
            o0 += p0[cc] * w;
            o1 += p1[cc] * w;
        }
        red[half][c][0] = o0; red[half][c][1] = o1;
    }
    __syncthreads();
    if (half == 0) {
        float bov = bo[n * DB + c];
        float O0 = red[0][c][0] + red[1][c][0] + bov;
        float O1 = red[0][c][1] + red[1][c][1] + bov;
        out[((size_t)(bt0 + 0) * NB + n) * DB + c] = O0;
        out[((size_t)(bt0 + 1) * NB + n) * DB + c] = O1;
    }
}

extern "C" void kernel_launch(void* const* d_in, const int* in_sizes, int n_in,
                              void* d_out, int out_size, void* d_ws, size_t ws_size,
                              hipStream_t stream) {
    const float* x  = (const float*)d_in[0];
    const float* g  = (const float*)d_in[1];
    const float* b  = (const float*)d_in[2];
    const float* q  = (const float*)d_in[3];
    const float* Wk = (const float*)d_in[4];
    const float* bk = (const float*)d_in[5];
    const float* Wv = (const float*)d_in[6];
    const float* bv = (const float*)d_in[7];
    const float* Wo = (const float*)d_in[8];
    const float* bo = (const float*)d_in[9];
    float* out = (float*)d_out;
    float* ws  = (float*)d_ws;

    hipLaunchKernelGGL(kP, dim3(256),    dim3(256), 0, stream, Wk, q, g, b, ws);
    hipLaunchKernelGGL(kA, dim3(512),    dim3(256), 0, stream, x, ws);
    hipLaunchKernelGGL(kC, dim3(128, 4), dim3(256), 0, stream, x, q, bk, ws);
    hipLaunchKernelGGL(kD, dim3(256),    dim3(512), 0, stream, Wv, Wo, g, b, bv, bo, ws, out);
}

// Round 7
// 273.164 us; speedup vs baseline: 1.1778x; 1.1778x over previous
//
#include <hip/hip_runtime.h>
#include <stdint.h>

#define BT      128
#define NPATCH  256
#define DV      1024
#define NB      4
#define DB      256
#define NH16    16
#define SCALE   0.125f
#define LNEPS   1e-5f

// ---- ws layout (float element offsets) ----
#define OFF_BWS    16384u      // 16384 bf16 (MFMA B-frags)
#define OFF_PSC    24608u      // 16 nh * 16 ich * 2 partial S/C
#define OFF_DRAW   25120u      // 32768*16
#define OFF_STATS  549408u     // 32768*2 (mu,rstd)
#define OFF_CV     1139232u    // 128*16
#define OFF_DIV    1141280u    // 768
#define OFF_XBAR   1142048u    // 4 slices * 2097152 bf16
#define OFF_POOL   9530656u    // 4*128*256
#define XSLICE     2097152u    // elements per slice (ushort units)

#define LROW 264               // bf16 per LDS row (256 + 8 pad)

typedef short bf16x8 __attribute__((ext_vector_type(8)));
typedef float f32x4  __attribute__((ext_vector_type(4)));

__device__ __forceinline__ short f2bf(float f) {   // RNE
    union { float f; unsigned u; } v; v.f = f;
    unsigned u = v.u;
    unsigned r = (u + 0x7fffu + ((u >> 16) & 1u)) >> 16;
    return (short)r;
}

// pack two floats -> two truncated bf16 in one v_perm_b32 (MFMA input only)
__device__ __forceinline__ unsigned pk2(float lo, float hi) {
    union { float f; unsigned u; } a, b; a.f = lo; b.f = hi;
    return __builtin_amdgcn_perm(b.u, a.u, 0x07060302u);
}

// ---- P: wq dots + direct bf16 B-frag pack; 256 blocks = 16 nh x 16 ich ----
__global__ __launch_bounds__(256) void kP(const float* __restrict__ Wk,
                                          const float* __restrict__ q,
                                          const float* __restrict__ g,
                                          const float* __restrict__ b,
                                          float* __restrict__ ws) {
    const int nh = blockIdx.x >> 4, ich = blockIdx.x & 15;
    const int n = nh >> 2, h = nh & 3;
    __shared__ float qs[64];
    __shared__ float redS[4], redC[4];
    const int t = threadIdx.x;
    if (t < 64) qs[t] = q[nh * 64 + t];
    __syncthreads();
    const int r = t >> 2, qd = t & 3;
    const int i = ich * 64 + r;
    const float* wrow = Wk + ((size_t)n * DV + i) * DB + h * 64 + qd * 16;
    float acc = 0.f;
    #pragma unroll
    for (int d = 0; d < 16; d += 4) {
        float4 w4 = *(const float4*)(wrow + d);
        acc += w4.x * qs[qd * 16 + d]     + w4.y * qs[qd * 16 + d + 1]
             + w4.z * qs[qd * 16 + d + 2] + w4.w * qs[qd * 16 + d + 3];
    }
    acc += __shfl_xor(acc, 1);
    acc += __shfl_xor(acc, 2);             // full 64-d dot in all 4 qd lanes
    float gw = g[i] * acc;
    if (qd == 0) {
        unsigned short* bws = (unsigned short*)(ws + OFF_BWS);
        const int kt = i >> 5, oct = (r >> 3) & 3, j = r & 7;
        bws[((kt * 64 + oct * 16 + nh) << 3) + j] = (unsigned short)f2bf(gw);
    }
    float mS = (qd == 0) ? gw : 0.f;
    float mC = (qd == 0) ? b[i] * acc : 0.f;
    #pragma unroll
    for (int dd = 4; dd < 64; dd <<= 1) { mS += __shfl_xor(mS, dd); mC += __shfl_xor(mC, dd); }
    const int wave = t >> 6, lane = t & 63;
    if (lane == 0) { redS[wave] = mS; redC[wave] = mC; }
    __syncthreads();
    if (t == 0) {
        ws[OFF_PSC + (nh * 16 + ich) * 2 + 0] = redS[0] + redS[1] + redS[2] + redS[3];
        ws[OFF_PSC + (nh * 16 + ich) * 2 + 1] = redC[0] + redC[1] + redC[2] + redC[3];
    }
}

// ---- A: single-buffer LDS + register prefetch; 512 blocks x 64 rows ----
__global__ __launch_bounds__(256) void kA(const float* __restrict__ x,
                                          float* __restrict__ ws) {
    __shared__ unsigned short xs[64 * LROW];
    const int t = threadIdx.x;
    const int wv = t >> 6, lane = t & 63;
    const int m = lane & 15, oct = lane >> 4;
    const int row0 = blockIdx.x * 64;
    const bf16x8* bfp = (const bf16x8*)((const unsigned short*)(ws + OFF_BWS));
    const float* xb = x + (size_t)row0 * DV;

    float sum[16], sq[16];
    #pragma unroll
    for (int i = 0; i < 16; ++i) { sum[i] = 0.f; sq[i] = 0.f; }
    f32x4 acc = {0.f, 0.f, 0.f, 0.f};
    float4 r[16];

    auto loadr = [&](int c) {
        #pragma unroll
        for (int i = 0; i < 16; ++i)
            r[i] = *(const float4*)(xb + (size_t)(i * 4 + wv) * DV + c * 256 + lane * 4);
    };
    auto commit = [&]() {
        #pragma unroll
        for (int i = 0; i < 16; ++i) {
            float4 v = r[i];
            sum[i] += v.x + v.y + v.z + v.w;
            sq[i]  += v.x * v.x + v.y * v.y + v.z * v.z + v.w * v.w;
            uint2 pk; pk.x = pk2(v.x, v.y); pk.y = pk2(v.z, v.w);
            *(uint2*)&xs[(i * 4 + wv) * LROW + lane * 4] = pk;
        }
    };
    auto comp = [&](int c) {
        #pragma unroll
        for (int kt = 0; kt < 8; ++kt) {
            bf16x8 af = *(const bf16x8*)&xs[(wv * 16 + m) * LROW + kt * 32 + oct * 8];
            bf16x8 bf = bfp[(c * 8 + kt) * 64 + lane];
            acc = __builtin_amdgcn_mfma_f32_16x16x32_bf16(af, bf, acc, 0, 0, 0);
        }
    };

    loadr(0);
    for (int c = 0; c < 4; ++c) {
        __syncthreads();          // prior chunk's LDS reads done
        commit();                 // regs -> LDS (+ LN sums)
        __syncthreads();
        if (c < 3) loadr(c + 1);  // next chunk's global loads in flight
        comp(c);                  // MFMA from LDS
    }

    #pragma unroll
    for (int r2 = 0; r2 < 4; ++r2)
        ws[OFF_DRAW + (size_t)(row0 + wv * 16 + oct * 4 + r2) * 16 + m] = acc[r2];

    #pragma unroll
    for (int i = 0; i < 16; ++i) {
        float s = sum[i], q2 = sq[i];
        #pragma unroll
        for (int d = 1; d < 64; d <<= 1) { s += __shfl_xor(s, d); q2 += __shfl_xor(q2, d); }
        if (lane == 0) {
            const int row = row0 + i * 4 + wv;
            const float mu  = s * (1.f / 1024.f);
            const float var = q2 * (1.f / 1024.f) - mu * mu;
            float2 st; st.x = mu; st.y = rsqrtf(var + LNEPS);
            *(float2*)(ws + OFF_STATS + (size_t)row * 2) = st;
        }
    }
}

// ---- C: softmax rebuilt per block, then zraw pooling; bf16 XBAR store ----
__global__ __launch_bounds__(256) void kC(const float* __restrict__ x,
                                          const float* __restrict__ q,
                                          const float* __restrict__ bk,
                                          float* __restrict__ ws) {
    const int bt = blockIdx.x;
    const int qq = blockIdx.y;             // p-quarter
    const int t = threadIdx.x;
    __shared__ __attribute__((aligned(16))) float s_s[NH16 * NPATCH];   // 16 KB
    __shared__ __attribute__((aligned(16))) float aavg[NB * NPATCH];    // 4 KB
    __shared__ __attribute__((aligned(16))) float w_s[64 * 16];         // 4 KB
    __shared__ __attribute__((aligned(16))) float rstd_s[NPATCH];
    __shared__ __attribute__((aligned(16))) float mrs[NPATCH];
    __shared__ float Ss[NH16], Cbs[NH16];

    {
        const int nh = t >> 4, ich = t & 15;
        float S = ws[OFF_PSC + t * 2 + 0];
        float C = ws[OFF_PSC + t * 2 + 1];
        const int n2 = nh >> 2, h2 = nh & 3;
        const float* bkp = bk + n2 * DB + h2 * 64 + ich * 4;
        const float* qp  = q + nh * 64 + ich * 4;
        C += bkp[0] * qp[0] + bkp[1] * qp[1] + bkp[2] * qp[2] + bkp[3] * qp[3];
        #pragma unroll
        for (int d = 1; d < 16; d <<= 1) { S += __shfl_xor(S, d); C += __shfl_xor(C, d); }
        if (ich == 0) { Ss[nh] = S; Cbs[nh] = C; }
    }
    const size_t row = (size_t)bt * NPATCH + t;
    const float2 st = *(const float2*)(ws + OFF_STATS + row * 2);
    rstd_s[t] = st.y;
    mrs[t] = st.x * st.y;
    __syncthreads();

    const float* dr = ws + OFF_DRAW + row * 16;
    #pragma unroll
    for (int nh = 0; nh < NH16; ++nh)
        s_s[nh * NPATCH + t] = (st.y * (dr[nh] - st.x * Ss[nh]) + Cbs[nh]) * SCALE;
    __syncthreads();

    const int wave = t >> 6, lane = t & 63;
    for (int r = 0; r < 4; ++r) {
        const int nh = wave * 4 + r;
        float4 v = *(float4*)&s_s[nh * NPATCH + lane * 4];
        float mx = fmaxf(fmaxf(v.x, v.y), fmaxf(v.z, v.w));
        for (int d = 1; d < 64; d <<= 1) mx = fmaxf(mx, __shfl_xor(mx, d));
        float e0 = __expf(v.x - mx), e1 = __expf(v.y - mx);
        float e2 = __expf(v.z - mx), e3 = __expf(v.w - mx);
        float s = e0 + e1 + e2 + e3;
        for (int d = 1; d < 64; d <<= 1) s += __shfl_xor(s, d);
        float inv = 1.f / s;
        float4 a; a.x = e0 * inv; a.y = e1 * inv; a.z = e2 * inv; a.w = e3 * inv;
        *(float4*)&s_s[nh * NPATCH + lane * 4] = a;
    }
    __syncthreads();

    if (qq == 0) {
        for (int r = 0; r < 4; ++r) {
            const int nh = wave * 4 + r;
            float4 a4 = *(float4*)&s_s[nh * NPATCH + lane * 4];
            float4 m4 = *(float4*)&mrs[lane * 4];
            float dd = a4.x * m4.x + a4.y * m4.y + a4.z * m4.z + a4.w * m4.w;
            for (int d = 1; d < 64; d <<= 1) dd += __shfl_xor(dd, d);
            if (lane == 0) ws[OFF_CV + bt * NH16 + nh] = dd;
        }
        #pragma unroll
        for (int nb2 = 0; nb2 < NB; ++nb2)
            aavg[nb2 * NPATCH + t] = 0.25f * (s_s[(nb2 * 4 + 0) * NPATCH + t] + s_s[(nb2 * 4 + 1) * NPATCH + t]
                                            + s_s[(nb2 * 4 + 2) * NPATCH + t] + s_s[(nb2 * 4 + 3) * NPATCH + t]);
        __syncthreads();
        if (wave == 0) {
            float nrm[NB];
            #pragma unroll
            for (int nb2 = 0; nb2 < NB; ++nb2) {
                float4 v = *(float4*)&aavg[nb2 * NPATCH + lane * 4];
                float ss = v.x * v.x + v.y * v.y + v.z * v.z + v.w * v.w;
                for (int d = 1; d < 64; d <<= 1) ss += __shfl_xor(ss, d);
                nrm[nb2] = fmaxf(sqrtf(ss), 1e-8f);
            }
            int pi = 0;
            for (int i2 = 0; i2 < NB; ++i2)
                for (int j2 = i2 + 1; j2 < NB; ++j2) {
                    float4 va = *(float4*)&aavg[i2 * NPATCH + lane * 4];
                    float4 vb = *(float4*)&aavg[j2 * NPATCH + lane * 4];
                    float dd = va.x * vb.x + va.y * vb.y + va.z * vb.z + va.w * vb.w;
                    for (int d = 1; d < 64; d <<= 1) dd += __shfl_xor(dd, d);
                    if (lane == 0) ws[OFF_DIV + bt * 6 + pi] = dd / (nrm[i2] * nrm[j2]);
                    ++pi;
                }
        }
    }

    for (int idx = t; idx < 1024; idx += 256) {
        const int p = idx >> 4, nh = idx & 15;
        w_s[idx] = s_s[nh * NPATCH + qq * 64 + p] * rstd_s[qq * 64 + p];
    }
    __syncthreads();

    float4 acc[16];
    #pragma unroll
    for (int i = 0; i < 16; ++i) { acc[i].x = 0.f; acc[i].y = 0.f; acc[i].z = 0.f; acc[i].w = 0.f; }
    const float* xp = x + (size_t)(bt * NPATCH + qq * 64) * DV + t * 4;
    #define FMA4(k, wgt, xv) acc[k].x += (wgt) * xv.x; acc[k].y += (wgt) * xv.y; \
                             acc[k].z += (wgt) * xv.z; acc[k].w += (wgt) * xv.w;
    #define PBLOCK(p, xv) { \
        float4 a0 = *(const float4*)&w_s[(p) * 16 + 0]; \
        float4 a1 = *(const float4*)&w_s[(p) * 16 + 4]; \
        float4 a2 = *(const float4*)&w_s[(p) * 16 + 8]; \
        float4 a3 = *(const float4*)&w_s[(p) * 16 + 12]; \
        FMA4(0, a0.x, xv)  FMA4(1, a0.y, xv)  FMA4(2, a0.z, xv)  FMA4(3, a0.w, xv) \
        FMA4(4, a1.x, xv)  FMA4(5, a1.y, xv)  FMA4(6, a1.z, xv)  FMA4(7, a1.w, xv) \
        FMA4(8, a2.x, xv)  FMA4(9, a2.y, xv)  FMA4(10, a2.z, xv) FMA4(11, a2.w, xv) \
        FMA4(12, a3.x, xv) FMA4(13, a3.y, xv) FMA4(14, a3.z, xv) FMA4(15, a3.w, xv) }
    for (int p = 0; p < 16; ++p) {
        float4 xv0 = *(const float4*)(xp + (size_t)(p +  0) * DV);
        float4 xv1 = *(const float4*)(xp + (size_t)(p + 16) * DV);
        float4 xv2 = *(const float4*)(xp + (size_t)(p + 32) * DV);
        float4 xv3 = *(const float4*)(xp + (size_t)(p + 48) * DV);
        PBLOCK(p, xv0)
        PBLOCK(p + 16, xv1)
        PBLOCK(p + 32, xv2)
        PBLOCK(p + 48, xv3)
    }
    #undef PBLOCK
    #undef FMA4
    // bf16 RNE store (intermediates are L2/L3-resident)
    unsigned short* xb16 = (unsigned short*)(ws + OFF_XBAR);
    #pragma unroll
    for (int nh = 0; nh < 16; ++nh) {
        float4 a = acc[nh];
        uint2 pk;
        pk.x = (unsigned)(unsigned short)f2bf(a.x) | ((unsigned)(unsigned short)f2bf(a.y) << 16);
        pk.y = (unsigned)(unsigned short)f2bf(a.z) | ((unsigned)(unsigned short)f2bf(a.w) << 16);
        *(uint2*)&xb16[(size_t)qq * XSLICE + ((size_t)bt * NH16 + nh) * DV + t * 4] = pk;
    }
}

// ---- D1: pooled = (zraw - CV)*g@Wv; float4 Wv loads + wave ig-reduce ----
// grid 512 = 16 nh x 32 btg (4 bt). thread = (ci = t&15 -> 4 cols, ig = t>>4).
__global__ __launch_bounds__(256) void kD1(const float* __restrict__ Wv,
                                           const float* __restrict__ g,
                                           const float* __restrict__ b,
                                           const float* __restrict__ bv,
                                           float* __restrict__ ws) {
    const int nh = blockIdx.x & 15, btg = blockIdx.x >> 4;
    const int n = nh >> 2, h = nh & 3;
    const int bt0 = btg * 4, cb = h * 64;
    __shared__ __attribute__((aligned(16))) float xs[4][1024];          // 16 KB
    __shared__ __attribute__((aligned(16))) float gs[1024], bs[1024];   // 8 KB
    __shared__ __attribute__((aligned(16))) float red[4][16][32];       // 8 KB
    const int t = threadIdx.x;
    const unsigned short* xb16 = (const unsigned short*)(ws + OFF_XBAR);
    for (int e = t; e < 1024; e += 256) {
        const int bt = e >> 8, i4 = e & 255;
        const size_t b0 = ((size_t)(bt0 + bt) * NH16 + nh) * DV + i4 * 4;
        float sx = 0.f, sy = 0.f, sz = 0.f, sw = 0.f;
        #pragma unroll
        for (int qq = 0; qq < 4; ++qq) {
            uint2 pv = *(const uint2*)&xb16[b0 + (size_t)qq * XSLICE];
            union { unsigned u; float f; } c0, c1, c2, c3;
            c0.u = pv.x << 16; c1.u = pv.x & 0xffff0000u;
            c2.u = pv.y << 16; c3.u = pv.y & 0xffff0000u;
            sx += c0.f; sy += c1.f; sz += c2.f; sw += c3.f;
        }
        float4 s; s.x = sx; s.y = sy; s.z = sz; s.w = sw;
        *(float4*)&xs[bt][i4 * 4] = s;
    }
    for (int e = t; e < 1024; e += 256) { gs[e] = g[e]; bs[e] = b[e]; }
    __syncthreads();

    const int ci = t & 15, ig = t >> 4;
    const int wave = t >> 6, lane = t & 63;
    float acc[4][4] = {{0.f}};
    float gv[4] = {0.f, 0.f, 0.f, 0.f}, bvv[4] = {0.f, 0.f, 0.f, 0.f};
    const float* wvp = Wv + ((size_t)n * DV + ig * 64) * DB + cb + ci * 4;
    #pragma unroll 8
    for (int ii = 0; ii < 64; ++ii) {
        const int idx = (ii + ig) & 63;        // per-ig rotation: LDS bank spread
        const int i = ig * 64 + idx;
        float4 w4 = *(const float4*)(wvp + (size_t)idx * DB);
        float gg = gs[i], bb2 = bs[i];
        float q0 = gg * w4.x, q1 = gg * w4.y, q2 = gg * w4.z, q3 = gg * w4.w;
        gv[0] += q0; gv[1] += q1; gv[2] += q2; gv[3] += q3;
        bvv[0] += bb2 * w4.x; bvv[1] += bb2 * w4.y; bvv[2] += bb2 * w4.z; bvv[3] += bb2 * w4.w;
        #pragma unroll
        for (int l = 0; l < 4; ++l) {
            float z = xs[l][i];
            acc[l][0] += z * q0; acc[l][1] += z * q1; acc[l][2] += z * q2; acc[l][3] += z * q3;
        }
    }
    // reduce the 4 ig slices within this wave (lane>>4 axis)
    #pragma unroll
    for (int l = 0; l < 4; ++l)
        #pragma unroll
        for (int j = 0; j < 4; ++j) {
            float v = acc[l][j];
            v += __shfl_xor(v, 16); v += __shfl_xor(v, 32);
            acc[l][j] = v;
        }
    #pragma unroll
    for (int j = 0; j < 4; ++j) {
        float v = gv[j];  v += __shfl_xor(v, 16);  v += __shfl_xor(v, 32);  gv[j] = v;
        float w2 = bvv[j]; w2 += __shfl_xor(w2, 16); w2 += __shfl_xor(w2, 32); bvv[j] = w2;
    }
    if (lane < 16) {
        #pragma unroll
        for (int l = 0; l < 4; ++l)
            #pragma unroll
            for (int j = 0; j < 4; ++j) red[wave][ci][l * 4 + j] = acc[l][j];
        #pragma unroll
        for (int j = 0; j < 4; ++j) { red[wave][ci][16 + j] = gv[j]; red[wave][ci][20 + j] = bvv[j]; }
    }
    __syncthreads();
    // t -> (ci2, j2, l2): 16 x 4 x 4 = 256 outputs (4 bt x 64 cols)
    const int ci2 = t >> 4, j2 = (t >> 2) & 3, l2 = t & 3;
    float A  = red[0][ci2][l2 * 4 + j2] + red[1][ci2][l2 * 4 + j2]
             + red[2][ci2][l2 * 4 + j2] + red[3][ci2][l2 * 4 + j2];
    float GV = red[0][ci2][16 + j2] + red[1][ci2][16 + j2]
             + red[2][ci2][16 + j2] + red[3][ci2][16 + j2];
    float BV = red[0][ci2][20 + j2] + red[1][ci2][20 + j2]
             + red[2][ci2][20 + j2] + red[3][ci2][20 + j2];
    const int col = cb + ci2 * 4 + j2;
    float C = ws[OFF_CV + (bt0 + l2) * NH16 + nh];
    float base = bv[n * DB + col] + BV;
    ws[OFF_POOL + ((size_t)n * BT + bt0 + l2) * DB + col] = A - C * GV + base;
}

// ---- D2: out = pooled @ Wo + bo ; block 0 also finalizes diversity loss ----
__global__ __launch_bounds__(256) void kD2(const float* __restrict__ Wo,
                                           const float* __restrict__ bo,
                                           const float* __restrict__ ws,
                                           float* __restrict__ out) {
    const int btg = blockIdx.x & 15, jq = (blockIdx.x >> 4) & 3, n = blockIdx.x >> 6;
    const int bt0 = btg * 8, j0 = jq * 64;
    __shared__ __attribute__((aligned(16))) float ps[8][256];
    __shared__ float red[4][64][8];
    __shared__ float dred[4];
    const int t = threadIdx.x;
    for (int e = t; e < 512; e += 256) {
        const int bt = e >> 6, c4 = e & 63;
        *(float4*)&ps[bt][c4 * 4] =
            *(const float4*)(ws + OFF_POOL + ((size_t)n * BT + bt0 + bt) * DB + c4 * 4);
    }
    float dacc = 0.f;
    if (blockIdx.x == 0)
        for (int idx = t; idx < 768; idx += 256) dacc += ws[OFF_DIV + idx];
    for (int d = 1; d < 64; d <<= 1) dacc += __shfl_xor(dacc, d);
    if ((t & 63) == 0) dred[t >> 6] = dacc;
    __syncthreads();
    if (blockIdx.x == 0 && t == 0)
        out[131072] = 0.1f * (dred[0] + dred[1] + dred[2] + dred[3]) / 768.f;
    const int j = t & 63, sub = t >> 6;
    float acc[8];
    #pragma unroll
    for (int l = 0; l < 8; ++l) acc[l] = 0.f;
    const float* wop = Wo + ((size_t)n * DB + sub * 64) * DB + j0 + j;
    const int cb0 = sub * 64;
    #pragma unroll 2
    for (int gidx = 0; gidx < 16; ++gidx) {
        const int cb = cb0 + gidx * 4;
        float w0 = wop[(size_t)(gidx * 4 + 0) * DB];
        float w1 = wop[(size_t)(gidx * 4 + 1) * DB];
        float w2 = wop[(size_t)(gidx * 4 + 2) * DB];
        float w3 = wop[(size_t)(gidx * 4 + 3) * DB];
        #pragma unroll
        for (int l = 0; l < 8; ++l) {
            float4 pr = *(const float4*)&ps[l][cb];
            acc[l] += pr.x * w0 + pr.y * w1 + pr.z * w2 + pr.w * w3;
        }
    }
    #pragma unroll
    for (int l = 0; l < 8; ++l) red[sub][j][l] = acc[l];
    __syncthreads();
    const int j2 = t & 63, l0 = t >> 6;
    float bov = bo[n * DB + j0 + j2];
    #pragma unroll
    for (int li = 0; li < 2; ++li) {
        const int l = l0 + li * 4;
        float o = red[0][j2][l] + red[1][j2][l] + red[2][j2][l] + red[3][j2][l] + bov;
        out[((size_t)(bt0 + l) * NB + n) * DB + j0 + j2] = o;
    }
}

extern "C" void kernel_launch(void* const* d_in, const int* in_sizes, int n_in,
                              void* d_out, int out_size, void* d_ws, size_t ws_size,
                              hipStream_t stream) {
    const float* x  = (const float*)d_in[0];
    const float* g  = (const float*)d_in[1];
    const float* b  = (const float*)d_in[2];
    const float* q  = (const float*)d_in[3];
    const float* Wk = (const float*)d_in[4];
    const float* bk = (const float*)d_in[5];
    const float* Wv = (const float*)d_in[6];
    const float* bv = (const float*)d_in[7];
    const float* Wo = (const float*)d_in[8];
    const float* bo = (const float*)d_in[9];
    float* out = (float*)d_out;
    float* ws  = (float*)d_ws;

    hipLaunchKernelGGL(kP,  dim3(256),    dim3(256), 0, stream, Wk, q, g, b, ws);
    hipLaunchKernelGGL(kA,  dim3(512),    dim3(256), 0, stream, x, ws);
    hipLaunchKernelGGL(kC,  dim3(128, 4), dim3(256), 0, stream, x, q, bk, ws);
    hipLaunchKernelGGL(kD1, dim3(512),    dim3(256), 0, stream, Wv, g, b, bv, ws);
    hipLaunchKernelGGL(kD2, dim3(256),    dim3(256), 0, stream, Wo, bo, ws, out);
}

// Round 8
// 273.053 us; speedup vs baseline: 1.1783x; 1.0004x over previous
//
#include <hip/hip_runtime.h>
#include <stdint.h>

#define BT      128
#define NPATCH  256
#define DV      1024
#define NB      4
#define DB      256
#define NH16    16
#define SCALE   0.125f
#define LNEPS   1e-5f

// ---- ws layout (float element offsets) ----
#define OFF_BWS    16384u      // 16384 bf16 (MFMA B-frags)
#define OFF_PSC    24608u      // 16 nh * 16 ich * 2 partial S/C
#define OFF_DRAW   25120u      // 32768*16
#define OFF_STATS  549408u     // 32768*2 (mu,rstd)
#define OFF_CV     1139232u    // 128*16
#define OFF_DIV    1141280u    // 768
#define OFF_XBAR   1142048u    // 8 slices * 2097152 bf16 (fills reserved region)
#define OFF_POOL   9530656u    // 4*128*256
#define XSLICE     2097152u    // ushort elements per slice

#define LROW 264               // bf16 per LDS row (256 + 8 pad)

typedef short bf16x8 __attribute__((ext_vector_type(8)));
typedef float f32x4  __attribute__((ext_vector_type(4)));

__device__ __forceinline__ short f2bf(float f) {   // RNE
    union { float f; unsigned u; } v; v.f = f;
    unsigned u = v.u;
    unsigned r = (u + 0x7fffu + ((u >> 16) & 1u)) >> 16;
    return (short)r;
}

// pack two floats -> two truncated bf16 in one v_perm_b32 (MFMA input only)
__device__ __forceinline__ unsigned pk2(float lo, float hi) {
    union { float f; unsigned u; } a, b; a.f = lo; b.f = hi;
    return __builtin_amdgcn_perm(b.u, a.u, 0x07060302u);
}

// ---- P: wq dots + direct bf16 B-frag pack; 256 blocks = 16 nh x 16 ich ----
__global__ __launch_bounds__(256) void kP(const float* __restrict__ Wk,
                                          const float* __restrict__ q,
                                          const float* __restrict__ g,
                                          const float* __restrict__ b,
                                          float* __restrict__ ws) {
    const int nh = blockIdx.x >> 4, ich = blockIdx.x & 15;
    const int n = nh >> 2, h = nh & 3;
    __shared__ float qs[64];
    __shared__ float redS[4], redC[4];
    const int t = threadIdx.x;
    if (t < 64) qs[t] = q[nh * 64 + t];
    __syncthreads();
    const int r = t >> 2, qd = t & 3;
    const int i = ich * 64 + r;
    const float* wrow = Wk + ((size_t)n * DV + i) * DB + h * 64 + qd * 16;
    float acc = 0.f;
    #pragma unroll
    for (int d = 0; d < 16; d += 4) {
        float4 w4 = *(const float4*)(wrow + d);
        acc += w4.x * qs[qd * 16 + d]     + w4.y * qs[qd * 16 + d + 1]
             + w4.z * qs[qd * 16 + d + 2] + w4.w * qs[qd * 16 + d + 3];
    }
    acc += __shfl_xor(acc, 1);
    acc += __shfl_xor(acc, 2);             // full 64-d dot in all 4 qd lanes
    float gw = g[i] * acc;
    if (qd == 0) {
        unsigned short* bws = (unsigned short*)(ws + OFF_BWS);
        const int kt = i >> 5, oct = (r >> 3) & 3, j = r & 7;
        bws[((kt * 64 + oct * 16 + nh) << 3) + j] = (unsigned short)f2bf(gw);
    }
    float mS = (qd == 0) ? gw : 0.f;
    float mC = (qd == 0) ? b[i] * acc : 0.f;
    #pragma unroll
    for (int dd = 4; dd < 64; dd <<= 1) { mS += __shfl_xor(mS, dd); mC += __shfl_xor(mC, dd); }
    const int wave = t >> 6, lane = t & 63;
    if (lane == 0) { redS[wave] = mS; redC[wave] = mC; }
    __syncthreads();
    if (t == 0) {
        ws[OFF_PSC + (nh * 16 + ich) * 2 + 0] = redS[0] + redS[1] + redS[2] + redS[3];
        ws[OFF_PSC + (nh * 16 + ich) * 2 + 1] = redC[0] + redC[1] + redC[2] + redC[3];
    }
}

// ---- A: single-buffer LDS + register prefetch; 512 blocks x 64 rows ----
__global__ __launch_bounds__(256) void kA(const float* __restrict__ x,
                                          float* __restrict__ ws) {
    __shared__ unsigned short xs[64 * LROW];
    const int t = threadIdx.x;
    const int wv = t >> 6, lane = t & 63;
    const int m = lane & 15, oct = lane >> 4;
    const int row0 = blockIdx.x * 64;
    const bf16x8* bfp = (const bf16x8*)((const unsigned short*)(ws + OFF_BWS));
    const float* xb = x + (size_t)row0 * DV;

    float sum[16], sq[16];
    #pragma unroll
    for (int i = 0; i < 16; ++i) { sum[i] = 0.f; sq[i] = 0.f; }
    f32x4 acc = {0.f, 0.f, 0.f, 0.f};
    float4 r[16];

    auto loadr = [&](int c) {
        #pragma unroll
        for (int i = 0; i < 16; ++i)
            r[i] = *(const float4*)(xb + (size_t)(i * 4 + wv) * DV + c * 256 + lane * 4);
    };
    auto commit = [&]() {
        #pragma unroll
        for (int i = 0; i < 16; ++i) {
            float4 v = r[i];
            sum[i] += v.x + v.y + v.z + v.w;
            sq[i]  += v.x * v.x + v.y * v.y + v.z * v.z + v.w * v.w;
            uint2 pk; pk.x = pk2(v.x, v.y); pk.y = pk2(v.z, v.w);
            *(uint2*)&xs[(i * 4 + wv) * LROW + lane * 4] = pk;
        }
    };
    auto comp = [&](int c) {
        #pragma unroll
        for (int kt = 0; kt < 8; ++kt) {
            bf16x8 af = *(const bf16x8*)&xs[(wv * 16 + m) * LROW + kt * 32 + oct * 8];
            bf16x8 bf = bfp[(c * 8 + kt) * 64 + lane];
            acc = __builtin_amdgcn_mfma_f32_16x16x32_bf16(af, bf, acc, 0, 0, 0);
        }
    };

    loadr(0);
    for (int c = 0; c < 4; ++c) {
        __syncthreads();          // prior chunk's LDS reads done
        commit();                 // regs -> LDS (+ LN sums)
        __syncthreads();
        if (c < 3) loadr(c + 1);  // next chunk's global loads in flight
        comp(c);                  // MFMA from LDS
    }

    #pragma unroll
    for (int r2 = 0; r2 < 4; ++r2)
        ws[OFF_DRAW + (size_t)(row0 + wv * 16 + oct * 4 + r2) * 16 + m] = acc[r2];

    #pragma unroll
    for (int i = 0; i < 16; ++i) {
        float s = sum[i], q2 = sq[i];
        #pragma unroll
        for (int d = 1; d < 64; d <<= 1) { s += __shfl_xor(s, d); q2 += __shfl_xor(q2, d); }
        if (lane == 0) {
            const int row = row0 + i * 4 + wv;
            const float mu  = s * (1.f / 1024.f);
            const float var = q2 * (1.f / 1024.f) - mu * mu;
            float2 st; st.x = mu; st.y = rsqrtf(var + LNEPS);
            *(float2*)(ws + OFF_STATS + (size_t)row * 2) = st;
        }
    }
}

// ---- C: softmax rebuilt per block, then zraw pooling over a 32-patch slice ----
// grid (128 bt, 8 qq): 1024 blocks -> 4 blocks/CU, 4 waves/SIMD (latency hiding)
__global__ __launch_bounds__(256) void kC(const float* __restrict__ x,
                                          const float* __restrict__ q,
                                          const float* __restrict__ bk,
                                          float* __restrict__ ws) {
    const int bt = blockIdx.x;
    const int qq = blockIdx.y;             // p-eighth (32 patches)
    const int t = threadIdx.x;
    __shared__ __attribute__((aligned(16))) float s_s[NH16 * NPATCH];   // 16 KB
    __shared__ __attribute__((aligned(16))) float aavg[NB * NPATCH];    // 4 KB
    __shared__ __attribute__((aligned(16))) float w_s[32 * 16];         // 2 KB
    __shared__ __attribute__((aligned(16))) float rstd_s[NPATCH];
    __shared__ __attribute__((aligned(16))) float mrs[NPATCH];
    __shared__ float Ss[NH16], Cbs[NH16];

    {
        const int nh = t >> 4, ich = t & 15;
        float S = ws[OFF_PSC + t * 2 + 0];
        float C = ws[OFF_PSC + t * 2 + 1];
        const int n2 = nh >> 2, h2 = nh & 3;
        const float* bkp = bk + n2 * DB + h2 * 64 + ich * 4;
        const float* qp  = q + nh * 64 + ich * 4;
        C += bkp[0] * qp[0] + bkp[1] * qp[1] + bkp[2] * qp[2] + bkp[3] * qp[3];
        #pragma unroll
        for (int d = 1; d < 16; d <<= 1) { S += __shfl_xor(S, d); C += __shfl_xor(C, d); }
        if (ich == 0) { Ss[nh] = S; Cbs[nh] = C; }
    }
    const size_t row = (size_t)bt * NPATCH + t;
    const float2 st = *(const float2*)(ws + OFF_STATS + row * 2);
    rstd_s[t] = st.y;
    mrs[t] = st.x * st.y;
    __syncthreads();

    const float* dr = ws + OFF_DRAW + row * 16;
    #pragma unroll
    for (int nh = 0; nh < NH16; ++nh)
        s_s[nh * NPATCH + t] = (st.y * (dr[nh] - st.x * Ss[nh]) + Cbs[nh]) * SCALE;
    __syncthreads();

    const int wave = t >> 6, lane = t & 63;
    for (int r = 0; r < 4; ++r) {
        const int nh = wave * 4 + r;
        float4 v = *(float4*)&s_s[nh * NPATCH + lane * 4];
        float mx = fmaxf(fmaxf(v.x, v.y), fmaxf(v.z, v.w));
        for (int d = 1; d < 64; d <<= 1) mx = fmaxf(mx, __shfl_xor(mx, d));
        float e0 = __expf(v.x - mx), e1 = __expf(v.y - mx);
        float e2 = __expf(v.z - mx), e3 = __expf(v.w - mx);
        float s = e0 + e1 + e2 + e3;
        for (int d = 1; d < 64; d <<= 1) s += __shfl_xor(s, d);
        float inv = 1.f / s;
        float4 a; a.x = e0 * inv; a.y = e1 * inv; a.z = e2 * inv; a.w = e3 * inv;
        *(float4*)&s_s[nh * NPATCH + lane * 4] = a;
    }
    __syncthreads();

    if (qq == 0) {
        for (int r = 0; r < 4; ++r) {
            const int nh = wave * 4 + r;
            float4 a4 = *(float4*)&s_s[nh * NPATCH + lane * 4];
            float4 m4 = *(float4*)&mrs[lane * 4];
            float dd = a4.x * m4.x + a4.y * m4.y + a4.z * m4.z + a4.w * m4.w;
            for (int d = 1; d < 64; d <<= 1) dd += __shfl_xor(dd, d);
            if (lane == 0) ws[OFF_CV + bt * NH16 + nh] = dd;
        }
        #pragma unroll
        for (int nb2 = 0; nb2 < NB; ++nb2)
            aavg[nb2 * NPATCH + t] = 0.25f * (s_s[(nb2 * 4 + 0) * NPATCH + t] + s_s[(nb2 * 4 + 1) * NPATCH + t]
                                            + s_s[(nb2 * 4 + 2) * NPATCH + t] + s_s[(nb2 * 4 + 3) * NPATCH + t]);
        __syncthreads();
        if (wave == 0) {
            float nrm[NB];
            #pragma unroll
            for (int nb2 = 0; nb2 < NB; ++nb2) {
                float4 v = *(float4*)&aavg[nb2 * NPATCH + lane * 4];
                float ss = v.x * v.x + v.y * v.y + v.z * v.z + v.w * v.w;
                for (int d = 1; d < 64; d <<= 1) ss += __shfl_xor(ss, d);
                nrm[nb2] = fmaxf(sqrtf(ss), 1e-8f);
            }
            int pi = 0;
            for (int i2 = 0; i2 < NB; ++i2)
                for (int j2 = i2 + 1; j2 < NB; ++j2) {
                    float4 va = *(float4*)&aavg[i2 * NPATCH + lane * 4];
                    float4 vb = *(float4*)&aavg[j2 * NPATCH + lane * 4];
                    float dd = va.x * vb.x + va.y * vb.y + va.z * vb.z + va.w * vb.w;
                    for (int d = 1; d < 64; d <<= 1) dd += __shfl_xor(dd, d);
                    if (lane == 0) ws[OFF_DIV + bt * 6 + pi] = dd / (nrm[i2] * nrm[j2]);
                    ++pi;
                }
        }
    }

    // pooling weights for this 32-patch slice
    for (int idx = t; idx < 512; idx += 256) {
        const int p = idx >> 4, nh = idx & 15;
        w_s[idx] = s_s[nh * NPATCH + qq * 32 + p] * rstd_s[qq * 32 + p];
    }
    __syncthreads();

    float4 acc[16];
    #pragma unroll
    for (int i = 0; i < 16; ++i) { acc[i].x = 0.f; acc[i].y = 0.f; acc[i].z = 0.f; acc[i].w = 0.f; }
    const float* xp = x + (size_t)(bt * NPATCH + qq * 32) * DV + t * 4;
    #define FMA4(k, wgt, xv) acc[k].x += (wgt) * xv.x; acc[k].y += (wgt) * xv.y; \
                             acc[k].z += (wgt) * xv.z; acc[k].w += (wgt) * xv.w;
    #define PBLOCK(p, xv) { \
        float4 a0 = *(const float4*)&w_s[(p) * 16 + 0]; \
        float4 a1 = *(const float4*)&w_s[(p) * 16 + 4]; \
        float4 a2 = *(const float4*)&w_s[(p) * 16 + 8]; \
        float4 a3 = *(const float4*)&w_s[(p) * 16 + 12]; \
        FMA4(0, a0.x, xv)  FMA4(1, a0.y, xv)  FMA4(2, a0.z, xv)  FMA4(3, a0.w, xv) \
        FMA4(4, a1.x, xv)  FMA4(5, a1.y, xv)  FMA4(6, a1.z, xv)  FMA4(7, a1.w, xv) \
        FMA4(8, a2.x, xv)  FMA4(9, a2.y, xv)  FMA4(10, a2.z, xv) FMA4(11, a2.w, xv) \
        FMA4(12, a3.x, xv) FMA4(13, a3.y, xv) FMA4(14, a3.z, xv) FMA4(15, a3.w, xv) }
    for (int p = 0; p < 8; ++p) {
        float4 xv0 = *(const float4*)(xp + (size_t)(p +  0) * DV);
        float4 xv1 = *(const float4*)(xp + (size_t)(p +  8) * DV);
        float4 xv2 = *(const float4*)(xp + (size_t)(p + 16) * DV);
        float4 xv3 = *(const float4*)(xp + (size_t)(p + 24) * DV);
        PBLOCK(p, xv0)
        PBLOCK(p + 8, xv1)
        PBLOCK(p + 16, xv2)
        PBLOCK(p + 24, xv3)
    }
    #undef PBLOCK
    #undef FMA4
    // bf16 RNE store (intermediates are L2/L3-resident)
    unsigned short* xb16 = (unsigned short*)(ws + OFF_XBAR);
    #pragma unroll
    for (int nh = 0; nh < 16; ++nh) {
        float4 a = acc[nh];
        uint2 pk;
        pk.x = (unsigned)(unsigned short)f2bf(a.x) | ((unsigned)(unsigned short)f2bf(a.y) << 16);
        pk.y = (unsigned)(unsigned short)f2bf(a.z) | ((unsigned)(unsigned short)f2bf(a.w) << 16);
        *(uint2*)&xb16[(size_t)qq * XSLICE + ((size_t)bt * NH16 + nh) * DV + t * 4] = pk;
    }
}

// ---- D1: pooled = (zraw - CV)*g@Wv; float4 Wv loads + wave ig-reduce ----
// grid 512 = 16 nh x 32 btg (4 bt). thread = (ci = t&15 -> 4 cols, ig = t>>4).
__global__ __launch_bounds__(256) void kD1(const float* __restrict__ Wv,
                                           const float* __restrict__ g,
                                           const float* __restrict__ b,
                                           const float* __restrict__ bv,
                                           float* __restrict__ ws) {
    const int nh = blockIdx.x & 15, btg = blockIdx.x >> 4;
    const int n = nh >> 2, h = nh & 3;
    const int bt0 = btg * 4, cb = h * 64;
    __shared__ __attribute__((aligned(16))) float xs[4][1024];          // 16 KB
    __shared__ __attribute__((aligned(16))) float gs[1024], bs[1024];   // 8 KB
    __shared__ __attribute__((aligned(16))) float red[4][16][32];       // 8 KB
    const int t = threadIdx.x;
    const unsigned short* xb16 = (const unsigned short*)(ws + OFF_XBAR);
    for (int e = t; e < 1024; e += 256) {
        const int bt = e >> 8, i4 = e & 255;
        const size_t b0 = ((size_t)(bt0 + bt) * NH16 + nh) * DV + i4 * 4;
        float sx = 0.f, sy = 0.f, sz = 0.f, sw = 0.f;
        #pragma unroll
        for (int qq = 0; qq < 8; ++qq) {
            uint2 pv = *(const uint2*)&xb16[b0 + (size_t)qq * XSLICE];
            union { unsigned u; float f; } c0, c1, c2, c3;
            c0.u = pv.x << 16; c1.u = pv.x & 0xffff0000u;
            c2.u = pv.y << 16; c3.u = pv.y & 0xffff0000u;
            sx += c0.f; sy += c1.f; sz += c2.f; sw += c3.f;
        }
        float4 s; s.x = sx; s.y = sy; s.z = sz; s.w = sw;
        *(float4*)&xs[bt][i4 * 4] = s;
    }
    for (int e = t; e < 1024; e += 256) { gs[e] = g[e]; bs[e] = b[e]; }
    __syncthreads();

    const int ci = t & 15, ig = t >> 4;
    const int wave = t >> 6, lane = t & 63;
    float acc[4][4] = {{0.f}};
    float gv[4] = {0.f, 0.f, 0.f, 0.f}, bvv[4] = {0.f, 0.f, 0.f, 0.f};
    const float* wvp = Wv + ((size_t)n * DV + ig * 64) * DB + cb + ci * 4;
    #pragma unroll 8
    for (int ii = 0; ii < 64; ++ii) {
        const int idx = (ii + ig) & 63;        // per-ig rotation: LDS bank spread
        const int i = ig * 64 + idx;
        float4 w4 = *(const float4*)(wvp + (size_t)idx * DB);
        float gg = gs[i], bb2 = bs[i];
        float q0 = gg * w4.x, q1 = gg * w4.y, q2 = gg * w4.z, q3 = gg * w4.w;
        gv[0] += q0; gv[1] += q1; gv[2] += q2; gv[3] += q3;
        bvv[0] += bb2 * w4.x; bvv[1] += bb2 * w4.y; bvv[2] += bb2 * w4.z; bvv[3] += bb2 * w4.w;
        #pragma unroll
        for (int l = 0; l < 4; ++l) {
            float z = xs[l][i];
            acc[l][0] += z * q0; acc[l][1] += z * q1; acc[l][2] += z * q2; acc[l][3] += z * q3;
        }
    }
    // reduce the 4 ig slices within this wave (lane>>4 axis)
    #pragma unroll
    for (int l = 0; l < 4; ++l)
        #pragma unroll
        for (int j = 0; j < 4; ++j) {
            float v = acc[l][j];
            v += __shfl_xor(v, 16); v += __shfl_xor(v, 32);
            acc[l][j] = v;
        }
    #pragma unroll
    for (int j = 0; j < 4; ++j) {
        float v = gv[j];  v += __shfl_xor(v, 16);  v += __shfl_xor(v, 32);  gv[j] = v;
        float w2 = bvv[j]; w2 += __shfl_xor(w2, 16); w2 += __shfl_xor(w2, 32); bvv[j] = w2;
    }
    if (lane < 16) {
        #pragma unroll
        for (int l = 0; l < 4; ++l)
            #pragma unroll
            for (int j = 0; j < 4; ++j) red[wave][ci][l * 4 + j] = acc[l][j];
        #pragma unroll
        for (int j = 0; j < 4; ++j) { red[wave][ci][16 + j] = gv[j]; red[wave][ci][20 + j] = bvv[j]; }
    }
    __syncthreads();
    // t -> (ci2, j2, l2): 16 x 4 x 4 = 256 outputs (4 bt x 64 cols)
    const int ci2 = t >> 4, j2 = (t >> 2) & 3, l2 = t & 3;
    float A  = red[0][ci2][l2 * 4 + j2] + red[1][ci2][l2 * 4 + j2]
             + red[2][ci2][l2 * 4 + j2] + red[3][ci2][l2 * 4 + j2];
    float GV = red[0][ci2][16 + j2] + red[1][ci2][16 + j2]
             + red[2][ci2][16 + j2] + red[3][ci2][16 + j2];
    float BV = red[0][ci2][20 + j2] + red[1][ci2][20 + j2]
             + red[2][ci2][20 + j2] + red[3][ci2][20 + j2];
    const int col = cb + ci2 * 4 + j2;
    float C = ws[OFF_CV + (bt0 + l2) * NH16 + nh];
    float base = bv[n * DB + col] + BV;
    ws[OFF_POOL + ((size_t)n * BT + bt0 + l2) * DB + col] = A - C * GV + base;
}

// ---- D2: out = pooled @ Wo + bo ; block 0 also finalizes diversity loss ----
__global__ __launch_bounds__(256) void kD2(const float* __restrict__ Wo,
                                           const float* __restrict__ bo,
                                           const float* __restrict__ ws,
                                           float* __restrict__ out) {
    const int btg = blockIdx.x & 15, jq = (blockIdx.x >> 4) & 3, n = blockIdx.x >> 6;
    const int bt0 = btg * 8, j0 = jq * 64;
    __shared__ __attribute__((aligned(16))) float ps[8][256];
    __shared__ float red[4][64][8];
    __shared__ float dred[4];
    const int t = threadIdx.x;
    for (int e = t; e < 512; e += 256) {
        const int bt = e >> 6, c4 = e & 63;
        *(float4*)&ps[bt][c4 * 4] =
            *(const float4*)(ws + OFF_POOL + ((size_t)n * BT + bt0 + bt) * DB + c4 * 4);
    }
    float dacc = 0.f;
    if (blockIdx.x == 0)
        for (int idx = t; idx < 768; idx += 256) dacc += ws[OFF_DIV + idx];
    for (int d = 1; d < 64; d <<= 1) dacc += __shfl_xor(dacc, d);
    if ((t & 63) == 0) dred[t >> 6] = dacc;
    __syncthreads();
    if (blockIdx.x == 0 && t == 0)
        out[131072] = 0.1f * (dred[0] + dred[1] + dred[2] + dred[3]) / 768.f;
    const int j = t & 63, sub = t >> 6;
    float acc[8];
    #pragma unroll
    for (int l = 0; l < 8; ++l) acc[l] = 0.f;
    const float* wop = Wo + ((size_t)n * DB + sub * 64) * DB + j0 + j;
    const int cb0 = sub * 64;
    #pragma unroll 2
    for (int gidx = 0; gidx < 16; ++gidx) {
        const int cb = cb0 + gidx * 4;
        float w0 = wop[(size_t)(gidx * 4 + 0) * DB];
        float w1 = wop[(size_t)(gidx * 4 + 1) * DB];
        float w2 = wop[(size_t)(gidx * 4 + 2) * DB];
        float w3 = wop[(size_t)(gidx * 4 + 3) * DB];
        #pragma unroll
        for (int l = 0; l < 8; ++l) {
            float4 pr = *(const float4*)&ps[l][cb];
            acc[l] += pr.x * w0 + pr.y * w1 + pr.z * w2 + pr.w * w3;
        }
    }
    #pragma unroll
    for (int l = 0; l < 8; ++l) red[sub][j][l] = acc[l];
    __syncthreads();
    const int j2 = t & 63, l0 = t >> 6;
    float bov = bo[n * DB + j0 + j2];
    #pragma unroll
    for (int li = 0; li < 2; ++li) {
        const int l = l0 + li * 4;
        float o = red[0][j2][l] + red[1][j2][l] + red[2][j2][l] + red[3][j2][l] + bov;
        out[((size_t)(bt0 + l) * NB + n) * DB + j0 + j2] = o;
    }
}

extern "C" void kernel_launch(void* const* d_in, const int* in_sizes, int n_in,
                              void* d_out, int out_size, void* d_ws, size_t ws_size,
                              hipStream_t stream) {
    const float* x  = (const float*)d_in[0];
    const float* g  = (const float*)d_in[1];
    const float* b  = (const float*)d_in[2];
    const float* q  = (const float*)d_in[3];
    const float* Wk = (const float*)d_in[4];
    const float* bk = (const float*)d_in[5];
    const float* Wv = (const float*)d_in[6];
    const float* bv = (const float*)d_in[7];
    const float* Wo = (const float*)d_in[8];
    const float* bo = (const float*)d_in[9];
    float* out = (float*)d_out;
    float* ws  = (float*)d_ws;

    hipLaunchKernelGGL(kP,  dim3(256),    dim3(256), 0, stream, Wk, q, g, b, ws);
    hipLaunchKernelGGL(kA,  dim3(512),    dim3(256), 0, stream, x, ws);
    hipLaunchKernelGGL(kC,  dim3(128, 8), dim3(256), 0, stream, x, q, bk, ws);
    hipLaunchKernelGGL(kD1, dim3(512),    dim3(256), 0, stream, Wv, g, b, bv, ws);
    hipLaunchKernelGGL(kD2, dim3(256),    dim3(256), 0, stream, Wo, bo, ws, out);
}